// Round 4
// baseline (977.094 us; speedup 1.0000x reference)
//
#include <hip/hip_runtime.h>

#define N_NODES   100000
#define D_DIM     16
#define NFILT     8
#define KOUT      128
#define NNZ_CNT   1600000

#define CBITS     7
#define CROWS     128                                  // rows per bucket
#define NCB       ((N_NODES + CROWS - 1) / CROWS)      // 782 buckets
#define CAP       2560                                 // slots per bucket (mean 2048, sigma 45)

// fp32 -> bf16 bits with round-to-nearest-even (same as __float2bfloat16)
__device__ __forceinline__ uint f32_to_bf16_bits(float f) {
    uint u = __float_as_uint(f);
    uint r = (u + 0x7FFFu + ((u >> 16) & 1u)) >> 16;
    return r;
}

// w_wav[n,f] = t^(2^f) - t^(2^(f+1)); fp32 compute, bf16 store (RNE)
__global__ void wav_kernel(const float* __restrict__ eig, ushort* __restrict__ wavb) {
    int n = blockIdx.x * blockDim.x + threadIdx.x;
    if (n >= N_NODES) return;
    float cur = expf(-eig[n]);
    uint pk[4];
#pragma unroll
    for (int h = 0; h < 4; ++h) {
        float nx0 = cur * cur;
        float w0 = cur - nx0;
        float nx1 = nx0 * nx0;
        float w1 = nx0 - nx1;
        cur = nx1;
        pk[h] = f32_to_bf16_bits(w0) | (f32_to_bf16_bits(w1) << 16);
    }
    *(uint4*)(wavb + (size_t)n * NFILT) = make_uint4(pk[0], pk[1], pk[2], pk[3]);
}

// Direct binning: bucket-contiguity is NOT needed within a bucket (binB treats
// buckets as unordered sets), so the whole block-local sort machinery of the
// old binA reduces to one returning atomic + one 8B store per edge.
// 1.6M atomics over 782 counters (~2K increments each, parallel chains);
// scattered 8B stores within bucket regions are absorbed/combined by L2.
// Record: x = ((key&127)<<17) | payload, y = bits of v.
__global__ __launch_bounds__(256) void bin_direct_kernel(const int* __restrict__ keys,
                                                         const int* __restrict__ pays,
                                                         const float* __restrict__ v,
                                                         int* __restrict__ gcur,
                                                         int2* __restrict__ regA) {
    int i = blockIdx.x * blockDim.x + threadIdx.x;
    if (i >= NNZ_CNT) return;
    int k = keys[i];
    int p = pays[i];
    float val = v[i];
    int b = k >> CBITS;
    int slot = atomicAdd(&gcur[b], 1);
    if (slot < CAP)
        regA[(size_t)b * CAP + slot] = make_int2(((k & (CROWS - 1)) << 17) | p,
                                                 __float_as_int(val));
}

// binB: one block per bucket; LDS count+scan over 128 keys; key-sorted records
// written back IN PLACE (block-private window); offs2[key] = {start, end}.
// CROWS=128: 782 balanced blocks (3/CU), rec = 20KB -> high occupancy.
__global__ __launch_bounds__(512) void binB_kernel(const int* __restrict__ gcur,
                                                   int2* __restrict__ regA,
                                                   int2* __restrict__ offs2) {
    __shared__ int2 rec[CAP];        // 20 KB
    __shared__ int cnt[CROWS];
    __shared__ int sc[CROWS];
    int tid = threadIdx.x;
    int b = blockIdx.x;
    int nb = gcur[b]; if (nb > CAP) nb = CAP;
    size_t base = (size_t)b * CAP;

    if (tid < CROWS) cnt[tid] = 0;
    __syncthreads();
    for (int i = tid; i < nb; i += 512) {
        int2 r = regA[base + i];
        rec[i] = r;
        atomicAdd(&cnt[r.x >> 17], 1);
    }
    __syncthreads();

    int cv = (tid < CROWS) ? cnt[tid] : 0;
    if (tid < CROWS) sc[tid] = cv;
    __syncthreads();
    for (int off = 1; off < CROWS; off <<= 1) {
        int t = (tid < CROWS && tid >= off) ? sc[tid - off] : 0;
        __syncthreads();
        if (tid < CROWS) sc[tid] += t;
        __syncthreads();
    }
    if (tid < CROWS) {
        int st = sc[tid] - cv;
        int key = b * CROWS + tid;
        if (key < N_NODES)
            offs2[key] = make_int2((int)base + st, (int)base + st + cv);
        cnt[tid] = st;   // becomes cursor
    }
    __syncthreads();

    for (int i = tid; i < nb; i += 512) {
        int2 r = rec[i];
        int p = atomicAdd(&cnt[r.x >> 17], 1);
        regA[base + p] = make_int2(r.x & 0x1FFFF, r.y);
    }
}

// Pass 1 gather: one wave per column.
// 4 sub-groups of 16 lanes each walk a quarter of the column's edges:
//   acc[d] += v * x[r][d]   (x row read = 64B fully coalesced, record is broadcast)
// then shfl_xor reduce across sub-groups and pack bf16 pairs {d, d+8} into LTxP.
__global__ __launch_bounds__(256) void gather1_kernel(const int2* __restrict__ offs2,
                                                      const int2* __restrict__ ep,
                                                      const float* __restrict__ x,
                                                      uint* __restrict__ LTxP) {
    int wave = (int)(((long long)blockIdx.x * blockDim.x + threadIdx.x) >> 6);
    if (wave >= N_NODES) return;
    int lane = threadIdx.x & 63;
    int c = wave;
    int d = lane & 15;         // feature dim
    int j = lane >> 4;         // sub-group 0..3
    int2 se = offs2[c];
    float acc = 0.f;
    for (int i = se.x + j; i < se.y; i += 4) {
        int2 e = ep[i];
        acc = fmaf(__int_as_float(e.y), x[(size_t)e.x * D_DIM + d], acc);
    }
    // reduce across the 4 sub-groups (lanes d, d+16, d+32, d+48)
    acc += __shfl_xor(acc, 16);
    acc += __shfl_xor(acc, 32);
    // lanes 0..15 hold LTx[c][d]; pack pairs {d, d+8} -> u32 (low=d, high=d+8)
    float hi = __shfl_down(acc, 8);
    if (lane < 8)
        LTxP[(size_t)c * NFILT + lane] = f32_to_bf16_bits(acc) | (f32_to_bf16_bits(hi) << 16);
}

// Pass 2 gather: one wave per row; lane owns outputs (lane) and (lane+64).
// bf16-packed operands: LTxP u32 = {bf16 d, bf16 d+8}, wav bf16.
// out stores are nontemporal: 51 MB of write-once full lines must not evict
// the 4.8 MB LTxP/wavb gather working set from L2.
__global__ __launch_bounds__(256) void gather2_kernel(const int2* __restrict__ offs2,
                                                      const int2* __restrict__ ep,
                                                      const uint* __restrict__ LTxP,
                                                      const ushort* __restrict__ wavb,
                                                      float* __restrict__ out) {
    int wave = (int)(((long long)blockIdx.x * blockDim.x + threadIdx.x) >> 6);
    if (wave >= N_NODES) return;
    int lane = threadIdx.x & 63;
    int r = wave;
    int d0 = lane >> 3;        // pair index 0..7
    int f  = lane & 7;         // 0..7
    int2 se = offs2[r];
    int i = se.x, end = se.y;
    float acc0 = 0.f, acc1 = 0.f;
    for (; i + 4 <= end; i += 4) {
        int2 e0 = ep[i], e1 = ep[i + 1], e2 = ep[i + 2], e3 = ep[i + 3];
        uint l0 = LTxP[e0.x * NFILT + d0];
        uint l1 = LTxP[e1.x * NFILT + d0];
        uint l2 = LTxP[e2.x * NFILT + d0];
        uint l3 = LTxP[e3.x * NFILT + d0];
        uint w0 = wavb[e0.x * NFILT + f];
        uint w1 = wavb[e1.x * NFILT + f];
        uint w2 = wavb[e2.x * NFILT + f];
        uint w3 = wavb[e3.x * NFILT + f];
        float vw0 = __int_as_float(e0.y) * __uint_as_float(w0 << 16);
        float vw1 = __int_as_float(e1.y) * __uint_as_float(w1 << 16);
        float vw2 = __int_as_float(e2.y) * __uint_as_float(w2 << 16);
        float vw3 = __int_as_float(e3.y) * __uint_as_float(w3 << 16);
        acc0 = fmaf(vw0, __uint_as_float(l0 << 16), acc0);
        acc1 = fmaf(vw0, __uint_as_float(l0 & 0xFFFF0000u), acc1);
        acc0 = fmaf(vw1, __uint_as_float(l1 << 16), acc0);
        acc1 = fmaf(vw1, __uint_as_float(l1 & 0xFFFF0000u), acc1);
        acc0 = fmaf(vw2, __uint_as_float(l2 << 16), acc0);
        acc1 = fmaf(vw2, __uint_as_float(l2 & 0xFFFF0000u), acc1);
        acc0 = fmaf(vw3, __uint_as_float(l3 << 16), acc0);
        acc1 = fmaf(vw3, __uint_as_float(l3 & 0xFFFF0000u), acc1);
    }
    for (; i < end; ++i) {
        int2 e = ep[i];
        uint l = LTxP[e.x * NFILT + d0];
        uint w = wavb[e.x * NFILT + f];
        float vw = __int_as_float(e.y) * __uint_as_float(w << 16);
        acc0 = fmaf(vw, __uint_as_float(l << 16), acc0);
        acc1 = fmaf(vw, __uint_as_float(l & 0xFFFF0000u), acc1);
    }
    __builtin_nontemporal_store(acc0, &out[(size_t)r * KOUT + lane]);
    __builtin_nontemporal_store(acc1, &out[(size_t)r * KOUT + 64 + lane]);
}

extern "C" void kernel_launch(void* const* d_in, const int* in_sizes, int n_in,
                              void* d_out, int out_size, void* d_ws, size_t ws_size,
                              hipStream_t stream) {
    const float* x      = (const float*)d_in[0];
    const int*   L_rows = (const int*)  d_in[1];
    const int*   L_cols = (const int*)  d_in[2];
    const float* L_v    = (const float*)d_in[3];
    const float* eig    = (const float*)d_in[4];
    float* out = (float*)d_out;

    // workspace layout (~22 MB); regA reused across the col-binned pass 1 and
    // row-binned pass 2 (stream-ordered).
    uint*   LTxP  = (uint*)d_ws;                              // [N*8]      3.2 MB (bf16 pairs)
    ushort* wavb  = (ushort*)(LTxP + (size_t)N_NODES * NFILT);// [N*8]      1.6 MB (bf16)
    int2*   offs2 = (int2*)(wavb + (size_t)N_NODES * NFILT);  // [N]        0.8 MB
    int2*   regA  = offs2 + N_NODES;                          // [NCB*CAP] 16.0 MB
    int*    gcur  = (int*)(regA + (size_t)NCB * CAP);         // [2*NCB]
    int*    gcurB = gcur + NCB;

    hipMemsetAsync(gcur, 0, (size_t)2 * NCB * sizeof(int), stream);

    wav_kernel<<<(N_NODES + 255) / 256, 256, 0, stream>>>(eig, wavb);

    // Pass 1: direct-bin by COLUMN, in-bucket sort (binB), atomic-free gather
    bin_direct_kernel<<<(NNZ_CNT + 255) / 256, 256, 0, stream>>>(L_cols, L_rows, L_v, gcurB, regA);
    binB_kernel<<<NCB, 512, 0, stream>>>(gcurB, regA, offs2);
    {
        long long threads = (long long)N_NODES * 64;   // one wave per column
        gather1_kernel<<<(int)((threads + 255) / 256), 256, 0, stream>>>(offs2, regA, x, LTxP);
    }

    // Pass 2: direct-bin by ROW (reusing regA), sort, gather
    bin_direct_kernel<<<(NNZ_CNT + 255) / 256, 256, 0, stream>>>(L_rows, L_cols, L_v, gcur, regA);
    binB_kernel<<<NCB, 512, 0, stream>>>(gcur, regA, offs2);
    {
        long long threads = (long long)N_NODES * 64;   // one wave per row
        gather2_kernel<<<(int)((threads + 255) / 256), 256, 0, stream>>>(offs2, regA, LTxP, wavb, out);
    }
}

// Round 5
// 392.924 us; speedup vs baseline: 2.4867x; 2.4867x over previous
//
#include <hip/hip_runtime.h>

#define N_NODES   100000
#define D_DIM     16
#define NFILT     8
#define KOUT      128
#define NNZ_CNT   1600000

#define CBITS     7
#define CROWS     128                                  // keys per bucket
#define NCB       ((N_NODES + CROWS - 1) / CROWS)      // 782 buckets
#define NSH       8                                    // cursor shards per bucket
#define CAPS      352                                  // slots per shard (mu 256 + ~6 sigma)
#define BSTRIDE   (NSH * CAPS)                         // 2816 slots per bucket
#define CAP       2560                                 // LDS sort capacity (bucket mu 2046 + ~11 sigma)
#define CPAD      16                                   // ints per cursor = one 64B line (atomics serialize per line!)

// fp32 -> bf16 bits with round-to-nearest-even (same as __float2bfloat16)
__device__ __forceinline__ uint f32_to_bf16_bits(float f) {
    uint u = __float_as_uint(f);
    uint r = (u + 0x7FFFu + ((u >> 16) & 1u)) >> 16;
    return r;
}

// w_wav[n,f] = t^(2^f) - t^(2^(f+1)); fp32 compute, bf16 store (RNE)
__global__ void wav_kernel(const float* __restrict__ eig, ushort* __restrict__ wavb) {
    int n = blockIdx.x * blockDim.x + threadIdx.x;
    if (n >= N_NODES) return;
    float cur = expf(-eig[n]);
    uint pk[4];
#pragma unroll
    for (int h = 0; h < 4; ++h) {
        float nx0 = cur * cur;
        float w0 = cur - nx0;
        float nx1 = nx0 * nx0;
        float w1 = nx0 - nx1;
        cur = nx1;
        pk[h] = f32_to_bf16_bits(w0) | (f32_to_bf16_bits(w1) << 16);
    }
    *(uint4*)(wavb + (size_t)n * NFILT) = make_uint4(pk[0], pk[1], pk[2], pk[3]);
}

// Direct binning with SHARDED, LINE-PADDED cursors.
// Round-4 lesson: atomics serialize per 64B line (~11.6 ns/op/line measured);
// 782 counters on 49 lines -> 377 us. With 8 shards x 64B padding: 256 ops/line
// -> ~3 us of serialization; the pass is then bound by its ~80 MB scatter traffic.
// Record: x = ((key&127)<<17) | payload, y = bits of v.
__global__ __launch_bounds__(256) void bin_kernel(const int* __restrict__ keys,
                                                  const int* __restrict__ pays,
                                                  const float* __restrict__ v,
                                                  int* __restrict__ gcur,
                                                  int2* __restrict__ regA) {
    int i = blockIdx.x * blockDim.x + threadIdx.x;
    if (i >= NNZ_CNT) return;
    int k = keys[i];
    int p = pays[i];
    float val = v[i];
    int b = k >> CBITS;
    int s = i & (NSH - 1);                 // lane-varying shard: no intra-wave same-line hits
    int slot = atomicAdd(&gcur[(b * NSH + s) * CPAD], 1);
    if (slot < CAPS)
        regA[(size_t)b * BSTRIDE + s * CAPS + slot] =
            make_int2(((k & (CROWS - 1)) << 17) | p, __float_as_int(val));
}

// Fused sort+gather for pass 1 (one block per COLUMN bucket).
// Load shard sub-ranges -> registers (1 rec/thread/shard) + LDS histogram,
// scan 128, scatter into col-sorted LDS rec[]; then the PROVEN gather1 scheme:
// per column, 16-lane x 4-subgroup walk (rec via free LDS broadcast, x row =
// coalesced 64B), shfl reduce, pack bf16 pairs {d,d+8} -> LTxP.
__global__ __launch_bounds__(512) void sortgather1_kernel(const int* __restrict__ gcur,
                                                          const int2* __restrict__ regA,
                                                          const float* __restrict__ x,
                                                          uint* __restrict__ LTxP) {
    __shared__ int2 rec[CAP];        // 20 KB, col-sorted: (row, vbits)
    __shared__ int cnt[CROWS];
    __shared__ int sc[CROWS];
    __shared__ int st[CROWS];
    __shared__ int cur[CROWS];
    int tid = threadIdx.x;
    int b = blockIdx.x;
    size_t base = (size_t)b * BSTRIDE;

    int2 my[NSH]; int mkey[NSH];
    if (tid < CROWS) cnt[tid] = 0;
    __syncthreads();
#pragma unroll
    for (int s = 0; s < NSH; ++s) {
        int c = gcur[(b * NSH + s) * CPAD]; if (c > CAPS) c = CAPS;
        mkey[s] = -1;
        if (tid < c) {
            my[s] = regA[base + s * CAPS + tid];
            mkey[s] = my[s].x >> 17;
            atomicAdd(&cnt[mkey[s]], 1);
        }
    }
    __syncthreads();

    int cv = (tid < CROWS) ? cnt[tid] : 0;
    if (tid < CROWS) sc[tid] = cv;
    __syncthreads();
    for (int off = 1; off < CROWS; off <<= 1) {
        int t = (tid < CROWS && tid >= off) ? sc[tid - off] : 0;
        __syncthreads();
        if (tid < CROWS) sc[tid] += t;
        __syncthreads();
    }
    if (tid < CROWS) { int s0 = sc[tid] - cv; st[tid] = s0; cur[tid] = s0; }
    __syncthreads();

#pragma unroll
    for (int s = 0; s < NSH; ++s)
        if (mkey[s] >= 0) {
            int pos = atomicAdd(&cur[mkey[s]], 1);
            if (pos < CAP) rec[pos] = make_int2(my[s].x & 0x1FFFF, my[s].y);
        }
    __syncthreads();

    // gather: 8 waves x 16 cols; lane = (j<<4)|d, 4 records in flight per col
    int wave = tid >> 6, lane = tid & 63;
    int d = lane & 15, j = lane >> 4;
    for (int cl = wave; cl < CROWS; cl += 8) {
        int c = b * CROWS + cl;
        int i0 = st[cl], e0 = i0 + cnt[cl]; if (e0 > CAP) e0 = CAP;
        float acc = 0.f;
        for (int i = i0 + j; i < e0; i += 4) {
            int2 e = rec[i];                         // 16-lane LDS broadcast
            acc = fmaf(__int_as_float(e.y), x[(size_t)e.x * D_DIM + d], acc);
        }
        acc += __shfl_xor(acc, 16);
        acc += __shfl_xor(acc, 32);
        float hi = __shfl_down(acc, 8);
        if (lane < 8 && c < N_NODES)
            LTxP[(size_t)c * NFILT + lane] =
                f32_to_bf16_bits(acc) | (f32_to_bf16_bits(hi) << 16);
    }
}

// Fused sort+gather for pass 2 (one block per ROW bucket).
// Same reg-staged LDS sort; then the PROVEN gather2 inner loop, with edge
// records via free LDS broadcast (whole wave reads the same 32B) instead of
// a global ep stream. out stores nontemporal: 51 MB of write-once lines must
// not evict the 4.8 MB LTxP/wavb working set.
__global__ __launch_bounds__(512) void sortgather2_kernel(const int* __restrict__ gcur,
                                                          const int2* __restrict__ regA,
                                                          const uint* __restrict__ LTxP,
                                                          const ushort* __restrict__ wavb,
                                                          float* __restrict__ out) {
    __shared__ int2 rec[CAP];        // 20 KB, row-sorted: (col, vbits)
    __shared__ int cnt[CROWS];
    __shared__ int sc[CROWS];
    __shared__ int st[CROWS];
    __shared__ int cur[CROWS];
    int tid = threadIdx.x;
    int b = blockIdx.x;
    size_t base = (size_t)b * BSTRIDE;

    int2 my[NSH]; int mkey[NSH];
    if (tid < CROWS) cnt[tid] = 0;
    __syncthreads();
#pragma unroll
    for (int s = 0; s < NSH; ++s) {
        int c = gcur[(b * NSH + s) * CPAD]; if (c > CAPS) c = CAPS;
        mkey[s] = -1;
        if (tid < c) {
            my[s] = regA[base + s * CAPS + tid];
            mkey[s] = my[s].x >> 17;
            atomicAdd(&cnt[mkey[s]], 1);
        }
    }
    __syncthreads();

    int cv = (tid < CROWS) ? cnt[tid] : 0;
    if (tid < CROWS) sc[tid] = cv;
    __syncthreads();
    for (int off = 1; off < CROWS; off <<= 1) {
        int t = (tid < CROWS && tid >= off) ? sc[tid - off] : 0;
        __syncthreads();
        if (tid < CROWS) sc[tid] += t;
        __syncthreads();
    }
    if (tid < CROWS) { int s0 = sc[tid] - cv; st[tid] = s0; cur[tid] = s0; }
    __syncthreads();

#pragma unroll
    for (int s = 0; s < NSH; ++s)
        if (mkey[s] >= 0) {
            int pos = atomicAdd(&cur[mkey[s]], 1);
            if (pos < CAP) rec[pos] = make_int2(my[s].x & 0x1FFFF, my[s].y);
        }
    __syncthreads();

    // gather: 8 waves x 16 rows; lane owns outputs (lane) and (lane+64)
    int wave = tid >> 6, lane = tid & 63;
    int d0 = lane >> 3;        // pair index 0..7
    int f  = lane & 7;         // 0..7
    for (int rl = wave; rl < CROWS; rl += 8) {
        int row = b * CROWS + rl;
        if (row >= N_NODES) continue;
        int i = st[rl], end = st[rl] + cnt[rl]; if (end > CAP) end = CAP;
        float acc0 = 0.f, acc1 = 0.f;
        for (; i + 4 <= end; i += 4) {
            int2 e0 = rec[i], e1 = rec[i + 1], e2 = rec[i + 2], e3 = rec[i + 3];
            uint l0 = LTxP[e0.x * NFILT + d0];
            uint l1 = LTxP[e1.x * NFILT + d0];
            uint l2 = LTxP[e2.x * NFILT + d0];
            uint l3 = LTxP[e3.x * NFILT + d0];
            uint w0 = wavb[e0.x * NFILT + f];
            uint w1 = wavb[e1.x * NFILT + f];
            uint w2 = wavb[e2.x * NFILT + f];
            uint w3 = wavb[e3.x * NFILT + f];
            float vw0 = __int_as_float(e0.y) * __uint_as_float(w0 << 16);
            float vw1 = __int_as_float(e1.y) * __uint_as_float(w1 << 16);
            float vw2 = __int_as_float(e2.y) * __uint_as_float(w2 << 16);
            float vw3 = __int_as_float(e3.y) * __uint_as_float(w3 << 16);
            acc0 = fmaf(vw0, __uint_as_float(l0 << 16), acc0);
            acc1 = fmaf(vw0, __uint_as_float(l0 & 0xFFFF0000u), acc1);
            acc0 = fmaf(vw1, __uint_as_float(l1 << 16), acc0);
            acc1 = fmaf(vw1, __uint_as_float(l1 & 0xFFFF0000u), acc1);
            acc0 = fmaf(vw2, __uint_as_float(l2 << 16), acc0);
            acc1 = fmaf(vw2, __uint_as_float(l2 & 0xFFFF0000u), acc1);
            acc0 = fmaf(vw3, __uint_as_float(l3 << 16), acc0);
            acc1 = fmaf(vw3, __uint_as_float(l3 & 0xFFFF0000u), acc1);
        }
        for (; i < end; ++i) {
            int2 e = rec[i];
            uint l = LTxP[e.x * NFILT + d0];
            uint w = wavb[e.x * NFILT + f];
            float vw = __int_as_float(e.y) * __uint_as_float(w << 16);
            acc0 = fmaf(vw, __uint_as_float(l << 16), acc0);
            acc1 = fmaf(vw, __uint_as_float(l & 0xFFFF0000u), acc1);
        }
        __builtin_nontemporal_store(acc0, &out[(size_t)row * KOUT + lane]);
        __builtin_nontemporal_store(acc1, &out[(size_t)row * KOUT + 64 + lane]);
    }
}

extern "C" void kernel_launch(void* const* d_in, const int* in_sizes, int n_in,
                              void* d_out, int out_size, void* d_ws, size_t ws_size,
                              hipStream_t stream) {
    const float* x      = (const float*)d_in[0];
    const int*   L_rows = (const int*)  d_in[1];
    const int*   L_cols = (const int*)  d_in[2];
    const float* L_v    = (const float*)d_in[3];
    const float* eig    = (const float*)d_in[4];
    float* out = (float*)d_out;

    // workspace layout (~23.2 MB); regA reused across the col-binned pass 1
    // and row-binned pass 2 (stream-ordered).
    uint*   LTxP  = (uint*)d_ws;                              // [N*8]          3.2 MB (bf16 pairs)
    ushort* wavb  = (ushort*)(LTxP + (size_t)N_NODES * NFILT);// [N*8]          1.6 MB (bf16)
    int2*   regA  = (int2*)(wavb + (size_t)N_NODES * NFILT);  // [NCB*BSTRIDE] 17.6 MB
    int*    gcur  = (int*)(regA + (size_t)NCB * BSTRIDE);     // [NCB*NSH*CPAD] 0.4 MB (line-padded cursors)
    int*    gcurB = gcur + (size_t)NCB * NSH * CPAD;          //                0.4 MB

    hipMemsetAsync(gcur, 0, (size_t)2 * NCB * NSH * CPAD * sizeof(int), stream);

    wav_kernel<<<(N_NODES + 255) / 256, 256, 0, stream>>>(eig, wavb);

    // Pass 1: sharded direct-bin by COLUMN, fused LDS sort + gather -> bf16 LTxP
    bin_kernel<<<(NNZ_CNT + 255) / 256, 256, 0, stream>>>(L_cols, L_rows, L_v, gcurB, regA);
    sortgather1_kernel<<<NCB, 512, 0, stream>>>(gcurB, regA, x, LTxP);

    // Pass 2: sharded direct-bin by ROW (reusing regA), fused LDS sort + gather
    bin_kernel<<<(NNZ_CNT + 255) / 256, 256, 0, stream>>>(L_rows, L_cols, L_v, gcur, regA);
    sortgather2_kernel<<<NCB, 512, 0, stream>>>(gcur, regA, LTxP, wavb, out);
}

// Round 6
// 277.933 us; speedup vs baseline: 3.5156x; 1.4137x over previous
//
#include <hip/hip_runtime.h>

#define N_NODES   100000
#define D_DIM     16
#define NFILT     8
#define KOUT      128
#define NNZ_CNT   1600000

// two-level binning geometry
#define SHIFT1    12
#define NC1       25                                   // coarse buckets (key>>12)
#define CAP1      67072                                // slots per coarse (mu 65536 + 6.1 sigma)
#define NSUB      32                                   // sub-buckets per coarse
#define CROWS     128                                  // keys per final bucket
#define NCB       (NC1 * NSUB)                         // 800 final buckets
#define CAP       2560                                 // final bucket slots (mu 2048 + 11 sigma)
#define EPB       2048                                 // edges/records per bin block
#define NBLKA     ((NNZ_CNT + EPB - 1) / EPB)          // 782 coarse blocks
#define CHB       ((CAP1 + EPB - 1) / EPB)             // 33 chunks per coarse in binF
#define CPAD      16                                   // ints per cursor = one 64B line

// fp32 -> bf16 bits with round-to-nearest-even (same as __float2bfloat16)
__device__ __forceinline__ uint f32_to_bf16_bits(float f) {
    uint u = __float_as_uint(f);
    uint r = (u + 0x7FFFu + ((u >> 16) & 1u)) >> 16;
    return r;
}

// w_wav[n,f] = t^(2^f) - t^(2^(f+1)); fp32 compute, bf16 store (RNE)
__global__ void wav_kernel(const float* __restrict__ eig, ushort* __restrict__ wavb) {
    int n = blockIdx.x * blockDim.x + threadIdx.x;
    if (n >= N_NODES) return;
    float cur = expf(-eig[n]);
    uint pk[4];
#pragma unroll
    for (int h = 0; h < 4; ++h) {
        float nx0 = cur * cur;
        float w0 = cur - nx0;
        float nx1 = nx0 * nx0;
        float w1 = nx0 - nx1;
        cur = nx1;
        pk[h] = f32_to_bf16_bits(w0) | (f32_to_bf16_bits(w1) << 16);
    }
    *(uint4*)(wavb + (size_t)n * NFILT) = make_uint4(pk[0], pk[1], pk[2], pk[3]);
}

// binC: coarse binning, 2048 edges -> 25 buckets (runs ~82 rec = 656B, coalesced).
// Round-5 lesson: single-level binning to 782 buckets = scattered 8B stores ->
// ~100 MB of 64B-line RMW writeback (WRITE_SIZE 93 MB, 115 us). Long runs fix it.
// Record: x = ((key & 4095) << 17) | payload   (12 key bits survive to binF).
__global__ __launch_bounds__(512) void binC_kernel(const int* __restrict__ keys,
                                                   const int* __restrict__ pays,
                                                   const float* __restrict__ v,
                                                   int* __restrict__ gcur1,
                                                   int2* __restrict__ regB) {
    __shared__ int cnt[NC1], offb[NC1], gbase[NC1], cur[NC1];
    __shared__ int2 rec[EPB];
    __shared__ unsigned char rbk[EPB];
    int tid = threadIdx.x;
    int e0 = blockIdx.x * EPB;
    int nE = NNZ_CNT - e0; if (nE > EPB) nE = EPB;

    if (tid < NC1) cnt[tid] = 0;
    __syncthreads();

    int k_[4], p_[4], vb_[4];
    int nk = 0;
#pragma unroll
    for (int kk = 0; kk < 4; ++kk) {
        int i = tid + kk * 512;
        if (i < nE) {
            k_[kk] = keys[e0 + i];
            p_[kk] = pays[e0 + i];
            vb_[kk] = __float_as_int(v[e0 + i]);
            nk = kk + 1;
            atomicAdd(&cnt[k_[kk] >> SHIFT1], 1);
        }
    }
    __syncthreads();

    if (tid == 0) {                       // trivial 25-element scan
        int run = 0;
        for (int b = 0; b < NC1; ++b) { offb[b] = run; run += cnt[b]; }
    }
    if (tid < NC1)
        gbase[tid] = cnt[tid] ? atomicAdd(&gcur1[tid * CPAD], cnt[tid]) : 0;
    __syncthreads();
    if (tid < NC1) cur[tid] = offb[tid];
    __syncthreads();

    for (int kk = 0; kk < nk; ++kk) {
        int b = k_[kk] >> SHIFT1;
        int pos = atomicAdd(&cur[b], 1);
        rec[pos] = make_int2(((k_[kk] & ((1 << SHIFT1) - 1)) << 17) | p_[kk], vb_[kk]);
        rbk[pos] = (unsigned char)b;
    }
    __syncthreads();

    // parallel copy-out: consecutive i -> consecutive dst within ~82-rec runs
    for (int i = tid; i < nE; i += 512) {
        int b = rbk[i];
        int slot = gbase[b] + (i - offb[b]);
        if (slot < CAP1) regB[(size_t)b * CAP1 + slot] = rec[i];
    }
}

// binF: fine binning. Block = one 2048-record chunk of one coarse bucket;
// bins into 32 sub-buckets (runs ~64 rec = 512B, coalesced). Record keeps
// 7 low key bits: x = (rowlow << 17) | payload  (mask 0xFFFFFF).
__global__ __launch_bounds__(512) void binF_kernel(const int* __restrict__ gcur1,
                                                   const int2* __restrict__ regB,
                                                   int* __restrict__ gcurF,
                                                   int2* __restrict__ regA) {
    __shared__ int cnt[NSUB], offb[NSUB], gbase[NSUB], cur[NSUB];
    __shared__ int2 rec[EPB];
    __shared__ unsigned char rbk[EPB];
    int tid = threadIdx.x;
    int cb = blockIdx.x / CHB;
    int ch = blockIdx.x % CHB;
    int nc = gcur1[cb * CPAD]; if (nc > CAP1) nc = CAP1;
    int cs = ch * EPB;
    if (cs >= nc) return;                 // uniform early-exit
    int nE = nc - cs; if (nE > EPB) nE = EPB;
    size_t srcb = (size_t)cb * CAP1 + cs;

    if (tid < NSUB) cnt[tid] = 0;
    __syncthreads();

    int2 my[4]; int msub[4];
    int nk = 0;
#pragma unroll
    for (int kk = 0; kk < 4; ++kk) {
        int i = tid + kk * 512;
        msub[kk] = -1;
        if (i < nE) {
            my[kk] = regB[srcb + i];
            msub[kk] = (my[kk].x >> 24) & (NSUB - 1);   // bits 24..28 = (key>>7)&31
            nk = kk + 1;
            atomicAdd(&cnt[msub[kk]], 1);
        }
    }
    __syncthreads();

    if (tid == 0) {
        int run = 0;
        for (int b = 0; b < NSUB; ++b) { offb[b] = run; run += cnt[b]; }
    }
    if (tid < NSUB)
        gbase[tid] = cnt[tid] ? atomicAdd(&gcurF[(cb * NSUB + tid) * CPAD], cnt[tid]) : 0;
    __syncthreads();
    if (tid < NSUB) cur[tid] = offb[tid];
    __syncthreads();

    for (int kk = 0; kk < nk; ++kk)
        if (msub[kk] >= 0) {
            int pos = atomicAdd(&cur[msub[kk]], 1);
            rec[pos] = make_int2(my[kk].x & 0xFFFFFF, my[kk].y);  // rowlow(7) | payload(17)
            rbk[pos] = (unsigned char)msub[kk];
        }
    __syncthreads();

    for (int i = tid; i < nE; i += 512) {
        int b = rbk[i];
        int slot = gbase[b] + (i - offb[b]);
        if (slot < CAP)
            regA[(size_t)(cb * NSUB + b) * CAP + slot] = rec[i];
    }
}

// Fused sort+gather for pass 1 (one block per COLUMN bucket, 128 cols).
// Contiguous record window -> registers + LDS histogram, scan 128, scatter
// into col-sorted LDS rec[]; then per column, 16-lane x 4-subgroup walk
// (rec via free LDS broadcast, x row = coalesced 64B), shfl reduce, pack
// bf16 pairs {d,d+8} -> LTxP.
__global__ __launch_bounds__(512) void sortgather1_kernel(const int* __restrict__ gcurF,
                                                          const int2* __restrict__ regA,
                                                          const float* __restrict__ x,
                                                          uint* __restrict__ LTxP) {
    __shared__ int2 rec[CAP];        // 20 KB, col-sorted: (row, vbits)
    __shared__ int cnt[CROWS];
    __shared__ int sc[CROWS];
    __shared__ int st[CROWS];
    __shared__ int cur[CROWS];
    int tid = threadIdx.x;
    int b = blockIdx.x;
    int nb = gcurF[b * CPAD]; if (nb > CAP) nb = CAP;
    size_t base = (size_t)b * CAP;

    int2 my[5]; int mkey[5];
    if (tid < CROWS) cnt[tid] = 0;
    __syncthreads();
#pragma unroll
    for (int s = 0; s < 5; ++s) {
        int i = tid + s * 512;
        mkey[s] = -1;
        if (i < nb) {
            my[s] = regA[base + i];
            mkey[s] = my[s].x >> 17;
            atomicAdd(&cnt[mkey[s]], 1);
        }
    }
    __syncthreads();

    int cv = (tid < CROWS) ? cnt[tid] : 0;
    if (tid < CROWS) sc[tid] = cv;
    __syncthreads();
    for (int off = 1; off < CROWS; off <<= 1) {
        int t = (tid < CROWS && tid >= off) ? sc[tid - off] : 0;
        __syncthreads();
        if (tid < CROWS) sc[tid] += t;
        __syncthreads();
    }
    if (tid < CROWS) { int s0 = sc[tid] - cv; st[tid] = s0; cur[tid] = s0; }
    __syncthreads();

#pragma unroll
    for (int s = 0; s < 5; ++s)
        if (mkey[s] >= 0) {
            int pos = atomicAdd(&cur[mkey[s]], 1);
            if (pos < CAP) rec[pos] = make_int2(my[s].x & 0x1FFFF, my[s].y);
        }
    __syncthreads();

    // gather: 8 waves x 16 cols; lane = (j<<4)|d, 4 records in flight per col
    int wave = tid >> 6, lane = tid & 63;
    int d = lane & 15, j = lane >> 4;
    for (int cl = wave; cl < CROWS; cl += 8) {
        int c = b * CROWS + cl;
        int i0 = st[cl], e0 = i0 + cnt[cl]; if (e0 > CAP) e0 = CAP;
        float acc = 0.f;
        for (int i = i0 + j; i < e0; i += 4) {
            int2 e = rec[i];                         // 16-lane LDS broadcast
            acc = fmaf(__int_as_float(e.y), x[(size_t)e.x * D_DIM + d], acc);
        }
        acc += __shfl_xor(acc, 16);
        acc += __shfl_xor(acc, 32);
        float hi = __shfl_down(acc, 8);
        if (lane < 8 && c < N_NODES)
            LTxP[(size_t)c * NFILT + lane] =
                f32_to_bf16_bits(acc) | (f32_to_bf16_bits(hi) << 16);
    }
}

// Fused sort+gather for pass 2 (one block per ROW bucket).
// Same reg-staged LDS sort; then the proven gather2 inner loop, with edge
// records via free LDS broadcast. out stores nontemporal: 51 MB of
// write-once lines must not evict the 4.8 MB LTxP/wavb working set.
__global__ __launch_bounds__(512) void sortgather2_kernel(const int* __restrict__ gcurF,
                                                          const int2* __restrict__ regA,
                                                          const uint* __restrict__ LTxP,
                                                          const ushort* __restrict__ wavb,
                                                          float* __restrict__ out) {
    __shared__ int2 rec[CAP];        // 20 KB, row-sorted: (col, vbits)
    __shared__ int cnt[CROWS];
    __shared__ int sc[CROWS];
    __shared__ int st[CROWS];
    __shared__ int cur[CROWS];
    int tid = threadIdx.x;
    int b = blockIdx.x;
    int nb = gcurF[b * CPAD]; if (nb > CAP) nb = CAP;
    size_t base = (size_t)b * CAP;

    int2 my[5]; int mkey[5];
    if (tid < CROWS) cnt[tid] = 0;
    __syncthreads();
#pragma unroll
    for (int s = 0; s < 5; ++s) {
        int i = tid + s * 512;
        mkey[s] = -1;
        if (i < nb) {
            my[s] = regA[base + i];
            mkey[s] = my[s].x >> 17;
            atomicAdd(&cnt[mkey[s]], 1);
        }
    }
    __syncthreads();

    int cv = (tid < CROWS) ? cnt[tid] : 0;
    if (tid < CROWS) sc[tid] = cv;
    __syncthreads();
    for (int off = 1; off < CROWS; off <<= 1) {
        int t = (tid < CROWS && tid >= off) ? sc[tid - off] : 0;
        __syncthreads();
        if (tid < CROWS) sc[tid] += t;
        __syncthreads();
    }
    if (tid < CROWS) { int s0 = sc[tid] - cv; st[tid] = s0; cur[tid] = s0; }
    __syncthreads();

#pragma unroll
    for (int s = 0; s < 5; ++s)
        if (mkey[s] >= 0) {
            int pos = atomicAdd(&cur[mkey[s]], 1);
            if (pos < CAP) rec[pos] = make_int2(my[s].x & 0x1FFFF, my[s].y);
        }
    __syncthreads();

    // gather: 8 waves x 16 rows; lane owns outputs (lane) and (lane+64)
    int wave = tid >> 6, lane = tid & 63;
    int d0 = lane >> 3;        // pair index 0..7
    int f  = lane & 7;         // 0..7
    for (int rl = wave; rl < CROWS; rl += 8) {
        int row = b * CROWS + rl;
        if (row >= N_NODES) continue;
        int i = st[rl], end = st[rl] + cnt[rl]; if (end > CAP) end = CAP;
        float acc0 = 0.f, acc1 = 0.f;
        for (; i + 4 <= end; i += 4) {
            int2 e0 = rec[i], e1 = rec[i + 1], e2 = rec[i + 2], e3 = rec[i + 3];
            uint l0 = LTxP[e0.x * NFILT + d0];
            uint l1 = LTxP[e1.x * NFILT + d0];
            uint l2 = LTxP[e2.x * NFILT + d0];
            uint l3 = LTxP[e3.x * NFILT + d0];
            uint w0 = wavb[e0.x * NFILT + f];
            uint w1 = wavb[e1.x * NFILT + f];
            uint w2 = wavb[e2.x * NFILT + f];
            uint w3 = wavb[e3.x * NFILT + f];
            float vw0 = __int_as_float(e0.y) * __uint_as_float(w0 << 16);
            float vw1 = __int_as_float(e1.y) * __uint_as_float(w1 << 16);
            float vw2 = __int_as_float(e2.y) * __uint_as_float(w2 << 16);
            float vw3 = __int_as_float(e3.y) * __uint_as_float(w3 << 16);
            acc0 = fmaf(vw0, __uint_as_float(l0 << 16), acc0);
            acc1 = fmaf(vw0, __uint_as_float(l0 & 0xFFFF0000u), acc1);
            acc0 = fmaf(vw1, __uint_as_float(l1 << 16), acc0);
            acc1 = fmaf(vw1, __uint_as_float(l1 & 0xFFFF0000u), acc1);
            acc0 = fmaf(vw2, __uint_as_float(l2 << 16), acc0);
            acc1 = fmaf(vw2, __uint_as_float(l2 & 0xFFFF0000u), acc1);
            acc0 = fmaf(vw3, __uint_as_float(l3 << 16), acc0);
            acc1 = fmaf(vw3, __uint_as_float(l3 & 0xFFFF0000u), acc1);
        }
        for (; i < end; ++i) {
            int2 e = rec[i];
            uint l = LTxP[e.x * NFILT + d0];
            uint w = wavb[e.x * NFILT + f];
            float vw = __int_as_float(e.y) * __uint_as_float(w << 16);
            acc0 = fmaf(vw, __uint_as_float(l << 16), acc0);
            acc1 = fmaf(vw, __uint_as_float(l & 0xFFFF0000u), acc1);
        }
        __builtin_nontemporal_store(acc0, &out[(size_t)row * KOUT + lane]);
        __builtin_nontemporal_store(acc1, &out[(size_t)row * KOUT + 64 + lane]);
    }
}

extern "C" void kernel_launch(void* const* d_in, const int* in_sizes, int n_in,
                              void* d_out, int out_size, void* d_ws, size_t ws_size,
                              hipStream_t stream) {
    const float* x      = (const float*)d_in[0];
    const int*   L_rows = (const int*)  d_in[1];
    const int*   L_cols = (const int*)  d_in[2];
    const float* L_v    = (const float*)d_in[3];
    const float* eig    = (const float*)d_in[4];
    float* out = (float*)d_out;

    // workspace layout (~34.7 MB); regB/regA reused across the col-ordered
    // pass 1 and row-ordered pass 2 (stream-ordered).
    uint*   LTxP = (uint*)d_ws;                               // [N*8]        3.2 MB
    ushort* wavb = (ushort*)(LTxP + (size_t)N_NODES * NFILT); // [N*8]        1.6 MB
    int2*   regB = (int2*)(wavb + (size_t)N_NODES * NFILT);   // [NC1*CAP1]  13.4 MB
    int2*   regA = regB + (size_t)NC1 * CAP1;                 // [NCB*CAP]   16.4 MB
    int*    gc1c = (int*)(regA + (size_t)NCB * CAP);          // coarse cursors (col)
    int*    gc1r = gc1c + NC1 * CPAD;                         // coarse cursors (row)
    int*    gfc  = gc1r + NC1 * CPAD;                         // final cursors (col)
    int*    gfr  = gfc + NCB * CPAD;                          // final cursors (row)

    hipMemsetAsync(gc1c, 0, (size_t)(2 * NC1 + 2 * NCB) * CPAD * sizeof(int), stream);

    wav_kernel<<<(N_NODES + 255) / 256, 256, 0, stream>>>(eig, wavb);

    // Pass 1: COLUMN ordering (coarse -> fine -> fused sort+gather -> bf16 LTxP)
    binC_kernel<<<NBLKA, 512, 0, stream>>>(L_cols, L_rows, L_v, gc1c, regB);
    binF_kernel<<<NC1 * CHB, 512, 0, stream>>>(gc1c, regB, gfc, regA);
    sortgather1_kernel<<<NCB, 512, 0, stream>>>(gfc, regA, x, LTxP);

    // Pass 2: ROW ordering (reusing regB/regA)
    binC_kernel<<<NBLKA, 512, 0, stream>>>(L_rows, L_cols, L_v, gc1r, regB);
    binF_kernel<<<NC1 * CHB, 512, 0, stream>>>(gc1r, regB, gfr, regA);
    sortgather2_kernel<<<NCB, 512, 0, stream>>>(gfr, regA, LTxP, wavb, out);
}

// Round 7
// 260.048 us; speedup vs baseline: 3.7574x; 1.0688x over previous
//
#include <hip/hip_runtime.h>

#define N_NODES   100000
#define D_DIM     16
#define NFILT     8
#define KOUT      128
#define NNZ_CNT   1600000

// two-level binning geometry
#define SHIFT1    12
#define NC1       25                                   // coarse buckets (key>>12)
#define CAP1      67072                                // slots per coarse (mu 64000 + ~12 sigma)
#define NSUB      64                                   // sub-buckets per coarse
#define CROWS     64                                   // keys per final bucket
#define NCB       (NC1 * NSUB)                         // 1600 final buckets
#define CAP       1408                                 // final bucket slots (mu 1024 + ~12 sigma)
#define EPB       2048                                 // edges/records per bin block
#define NBLKA     ((NNZ_CNT + EPB - 1) / EPB)          // 782 coarse blocks
#define CHB       ((CAP1 + EPB - 1) / EPB)             // 33 chunks per coarse in binF
#define CPAD      16                                   // ints per cursor = one 64B line

// combo[node] = 64B line: [0..7]=LTx bf16 pairs (u32), [8..11]=wav bf16 (u16 x8), [12..15] pad.
// One random line per gathered record in sortgather2 (was two: LTxP + wavb).

// fp32 -> bf16 bits with round-to-nearest-even (same as __float2bfloat16)
__device__ __forceinline__ uint f32_to_bf16_bits(float f) {
    uint u = __float_as_uint(f);
    uint r = (u + 0x7FFFu + ((u >> 16) & 1u)) >> 16;
    return r;
}

// w_wav[n,f] = t^(2^f) - t^(2^(f+1)); fp32 compute, bf16 store into combo[n][8..11]
__global__ void wav_kernel(const float* __restrict__ eig, uint* __restrict__ combo) {
    int n = blockIdx.x * blockDim.x + threadIdx.x;
    if (n >= N_NODES) return;
    float cur = expf(-eig[n]);
    uint pk[4];
#pragma unroll
    for (int h = 0; h < 4; ++h) {
        float nx0 = cur * cur;
        float w0 = cur - nx0;
        float nx1 = nx0 * nx0;
        float w1 = nx0 - nx1;
        cur = nx1;
        pk[h] = f32_to_bf16_bits(w0) | (f32_to_bf16_bits(w1) << 16);
    }
    *(uint4*)(combo + (size_t)n * 16 + 8) = make_uint4(pk[0], pk[1], pk[2], pk[3]);
}

// binC2: FUSED coarse binning for both orderings. Stages 2048 edges in
// registers ONCE (edge arrays read once, not twice), then runs two phases
// (key=col -> regBc, key=row -> regBr) reusing the same LDS machinery.
// Runs ~82 rec = 656B -> coalesced copy-out (round-5 lesson: scattered 8B
// stores cost ~100 MB of line RMW).
// Record: x = ((key & 4095) << 17) | payload   (12 key bits survive to binF).
__global__ __launch_bounds__(512) void binC2_kernel(const int* __restrict__ rows,
                                                    const int* __restrict__ cols,
                                                    const float* __restrict__ v,
                                                    int* __restrict__ gc1c,
                                                    int* __restrict__ gc1r,
                                                    int2* __restrict__ regBc,
                                                    int2* __restrict__ regBr) {
    __shared__ int cnt[NC1], offb[NC1], gbase[NC1], cur[NC1];
    __shared__ int2 rec[EPB];
    __shared__ unsigned char rbk[EPB];
    int tid = threadIdx.x;
    int e0 = blockIdx.x * EPB;
    int nE = NNZ_CNT - e0; if (nE > EPB) nE = EPB;

    int r_[4], c_[4], vb_[4];
    int nk = 0;
#pragma unroll
    for (int kk = 0; kk < 4; ++kk) {
        int i = tid + kk * 512;
        if (i < nE) {
            r_[kk] = rows[e0 + i];
            c_[kk] = cols[e0 + i];
            vb_[kk] = __float_as_int(v[e0 + i]);
            nk = kk + 1;
        }
    }

    // ---- phase A: key = col, payload = row -> regBc ----
    if (tid < NC1) cnt[tid] = 0;
    __syncthreads();
    for (int kk = 0; kk < nk; ++kk) atomicAdd(&cnt[c_[kk] >> SHIFT1], 1);
    __syncthreads();
    if (tid == 0) { int run = 0; for (int b = 0; b < NC1; ++b) { offb[b] = run; run += cnt[b]; } }
    __syncthreads();
    if (tid < NC1) {
        gbase[tid] = cnt[tid] ? atomicAdd(&gc1c[tid * CPAD], cnt[tid]) : 0;
        cur[tid] = offb[tid];
    }
    __syncthreads();
    for (int kk = 0; kk < nk; ++kk) {
        int b = c_[kk] >> SHIFT1;
        int pos = atomicAdd(&cur[b], 1);
        rec[pos] = make_int2(((c_[kk] & 4095) << 17) | r_[kk], vb_[kk]);
        rbk[pos] = (unsigned char)b;
    }
    __syncthreads();
    for (int i = tid; i < nE; i += 512) {
        int b = rbk[i];
        int slot = gbase[b] + (i - offb[b]);
        if (slot < CAP1) regBc[(size_t)b * CAP1 + slot] = rec[i];
    }
    __syncthreads();

    // ---- phase B: key = row, payload = col -> regBr ----
    if (tid < NC1) cnt[tid] = 0;
    __syncthreads();
    for (int kk = 0; kk < nk; ++kk) atomicAdd(&cnt[r_[kk] >> SHIFT1], 1);
    __syncthreads();
    if (tid == 0) { int run = 0; for (int b = 0; b < NC1; ++b) { offb[b] = run; run += cnt[b]; } }
    __syncthreads();
    if (tid < NC1) {
        gbase[tid] = cnt[tid] ? atomicAdd(&gc1r[tid * CPAD], cnt[tid]) : 0;
        cur[tid] = offb[tid];
    }
    __syncthreads();
    for (int kk = 0; kk < nk; ++kk) {
        int b = r_[kk] >> SHIFT1;
        int pos = atomicAdd(&cur[b], 1);
        rec[pos] = make_int2(((r_[kk] & 4095) << 17) | c_[kk], vb_[kk]);
        rbk[pos] = (unsigned char)b;
    }
    __syncthreads();
    for (int i = tid; i < nE; i += 512) {
        int b = rbk[i];
        int slot = gbase[b] + (i - offb[b]);
        if (slot < CAP1) regBr[(size_t)b * CAP1 + slot] = rec[i];
    }
}

// binF: fine binning. Block = one 2048-record chunk of one coarse bucket;
// bins into 64 sub-buckets (runs ~32 rec = 256B, coalesced-ish).
// sub = key bits 6..11 = record bits 23..28. Output keeps 6 low key bits:
// x = (keylow6 << 17) | payload  (mask 0x7FFFFF).
__global__ __launch_bounds__(512) void binF_kernel(const int* __restrict__ gcur1,
                                                   const int2* __restrict__ regB,
                                                   int* __restrict__ gcurF,
                                                   int2* __restrict__ regA) {
    __shared__ int cnt[NSUB], offb[NSUB], gbase[NSUB], cur[NSUB];
    __shared__ int2 rec[EPB];
    __shared__ unsigned char rbk[EPB];
    int tid = threadIdx.x;
    int cb = blockIdx.x / CHB;
    int ch = blockIdx.x % CHB;
    int nc = gcur1[cb * CPAD]; if (nc > CAP1) nc = CAP1;
    int cs = ch * EPB;
    if (cs >= nc) return;                 // uniform early-exit
    int nE = nc - cs; if (nE > EPB) nE = EPB;
    size_t srcb = (size_t)cb * CAP1 + cs;

    if (tid < NSUB) cnt[tid] = 0;
    __syncthreads();

    int2 my[4]; int msub[4];
    int nk = 0;
#pragma unroll
    for (int kk = 0; kk < 4; ++kk) {
        int i = tid + kk * 512;
        msub[kk] = -1;
        if (i < nE) {
            my[kk] = regB[srcb + i];
            msub[kk] = (my[kk].x >> 23) & (NSUB - 1);
            nk = kk + 1;
            atomicAdd(&cnt[msub[kk]], 1);
        }
    }
    __syncthreads();

    if (tid == 0) { int run = 0; for (int b = 0; b < NSUB; ++b) { offb[b] = run; run += cnt[b]; } }
    __syncthreads();
    if (tid < NSUB) {
        gbase[tid] = cnt[tid] ? atomicAdd(&gcurF[(cb * NSUB + tid) * CPAD], cnt[tid]) : 0;
        cur[tid] = offb[tid];
    }
    __syncthreads();

    for (int kk = 0; kk < nk; ++kk)
        if (msub[kk] >= 0) {
            int pos = atomicAdd(&cur[msub[kk]], 1);
            rec[pos] = make_int2(my[kk].x & 0x7FFFFF, my[kk].y);  // keylow(6) | payload(17)
            rbk[pos] = (unsigned char)msub[kk];
        }
    __syncthreads();

    for (int i = tid; i < nE; i += 512) {
        int b = rbk[i];
        int slot = gbase[b] + (i - offb[b]);
        if (slot < CAP)
            regA[(size_t)(cb * NSUB + b) * CAP + slot] = rec[i];
    }
}

// Fused sort+gather for pass 1 (one block per COLUMN bucket, 64 cols, 256 thr).
// Records -> registers + LDS histogram, scan 64, scatter into col-sorted LDS
// rec[]; then per column, 16-lane x 4-subgroup walk (rec via free LDS
// broadcast, x row = coalesced 64B), shfl reduce, pack bf16 pairs {d,d+8}
// into combo[c][0..7]. 1600 blocks -> ~6 blocks/CU (was 3.1 -> 41% occ).
__global__ __launch_bounds__(256) void sortgather1_kernel(const int* __restrict__ gcurF,
                                                          const int2* __restrict__ regA,
                                                          const float* __restrict__ x,
                                                          uint* __restrict__ combo) {
    __shared__ int2 rec[CAP];        // 11.3 KB, col-sorted: (row, vbits)
    __shared__ int cnt[CROWS], sc[CROWS], st[CROWS], cur[CROWS];
    int tid = threadIdx.x;
    int b = blockIdx.x;
    int nb = gcurF[b * CPAD]; if (nb > CAP) nb = CAP;
    size_t base = (size_t)b * CAP;

    int2 my[6]; int mkey[6];
    if (tid < CROWS) cnt[tid] = 0;
    __syncthreads();
#pragma unroll
    for (int s = 0; s < 6; ++s) {
        int i = tid + s * 256;
        mkey[s] = -1;
        if (i < nb) {
            my[s] = regA[base + i];
            mkey[s] = my[s].x >> 17;
            atomicAdd(&cnt[mkey[s]], 1);
        }
    }
    __syncthreads();

    int cv = (tid < CROWS) ? cnt[tid] : 0;
    if (tid < CROWS) sc[tid] = cv;
    __syncthreads();
    for (int off = 1; off < CROWS; off <<= 1) {
        int t = (tid < CROWS && tid >= off) ? sc[tid - off] : 0;
        __syncthreads();
        if (tid < CROWS) sc[tid] += t;
        __syncthreads();
    }
    if (tid < CROWS) { int s0 = sc[tid] - cv; st[tid] = s0; cur[tid] = s0; }
    __syncthreads();

#pragma unroll
    for (int s = 0; s < 6; ++s)
        if (mkey[s] >= 0) {
            int pos = atomicAdd(&cur[mkey[s]], 1);
            if (pos < CAP) rec[pos] = make_int2(my[s].x & 0x1FFFF, my[s].y);
        }
    __syncthreads();

    // gather: 4 waves x 16 cols; lane = (j<<4)|d, 4 records in flight per col
    int wave = tid >> 6, lane = tid & 63;
    int d = lane & 15, j = lane >> 4;
    for (int cl = wave; cl < CROWS; cl += 4) {
        int c = b * CROWS + cl;
        int i0 = st[cl], e0 = i0 + cnt[cl]; if (e0 > CAP) e0 = CAP;
        float acc = 0.f;
        for (int i = i0 + j; i < e0; i += 4) {
            int2 e = rec[i];                         // 16-lane LDS broadcast
            acc = fmaf(__int_as_float(e.y), x[(size_t)e.x * D_DIM + d], acc);
        }
        acc += __shfl_xor(acc, 16);
        acc += __shfl_xor(acc, 32);
        float hi = __shfl_down(acc, 8);
        if (lane < 8 && c < N_NODES)
            combo[(size_t)c * 16 + lane] =
                f32_to_bf16_bits(acc) | (f32_to_bf16_bits(hi) << 16);
    }
}

// Fused sort+gather for pass 2 (one block per ROW bucket, 64 rows, 256 thr).
// Same reg-staged LDS sort; gather reads ONE combo line per record
// (LTx pairs + wav in the same 64B). out stores nontemporal: 51 MB of
// write-once lines must not evict the 6.4 MB combo working set.
__global__ __launch_bounds__(256) void sortgather2_kernel(const int* __restrict__ gcurF,
                                                          const int2* __restrict__ regA,
                                                          const uint* __restrict__ combo,
                                                          float* __restrict__ out) {
    __shared__ int2 rec[CAP];        // 11.3 KB, row-sorted: (col, vbits)
    __shared__ int cnt[CROWS], sc[CROWS], st[CROWS], cur[CROWS];
    int tid = threadIdx.x;
    int b = blockIdx.x;
    int nb = gcurF[b * CPAD]; if (nb > CAP) nb = CAP;
    size_t base = (size_t)b * CAP;

    int2 my[6]; int mkey[6];
    if (tid < CROWS) cnt[tid] = 0;
    __syncthreads();
#pragma unroll
    for (int s = 0; s < 6; ++s) {
        int i = tid + s * 256;
        mkey[s] = -1;
        if (i < nb) {
            my[s] = regA[base + i];
            mkey[s] = my[s].x >> 17;
            atomicAdd(&cnt[mkey[s]], 1);
        }
    }
    __syncthreads();

    int cv = (tid < CROWS) ? cnt[tid] : 0;
    if (tid < CROWS) sc[tid] = cv;
    __syncthreads();
    for (int off = 1; off < CROWS; off <<= 1) {
        int t = (tid < CROWS && tid >= off) ? sc[tid - off] : 0;
        __syncthreads();
        if (tid < CROWS) sc[tid] += t;
        __syncthreads();
    }
    if (tid < CROWS) { int s0 = sc[tid] - cv; st[tid] = s0; cur[tid] = s0; }
    __syncthreads();

#pragma unroll
    for (int s = 0; s < 6; ++s)
        if (mkey[s] >= 0) {
            int pos = atomicAdd(&cur[mkey[s]], 1);
            if (pos < CAP) rec[pos] = make_int2(my[s].x & 0x1FFFF, my[s].y);
        }
    __syncthreads();

    // gather: 4 waves x 16 rows; lane owns outputs (lane) and (lane+64)
    int wave = tid >> 6, lane = tid & 63;
    int d0 = lane >> 3;        // pair index 0..7
    int f  = lane & 7;         // 0..7
    for (int rl = wave; rl < CROWS; rl += 4) {
        int row = b * CROWS + rl;
        if (row >= N_NODES) continue;
        int i = st[rl], end = st[rl] + cnt[rl]; if (end > CAP) end = CAP;
        float acc0 = 0.f, acc1 = 0.f;
        for (; i + 4 <= end; i += 4) {
            int2 e0 = rec[i], e1 = rec[i + 1], e2 = rec[i + 2], e3 = rec[i + 3];
            uint l0 = combo[(size_t)e0.x * 16 + d0];
            uint l1 = combo[(size_t)e1.x * 16 + d0];
            uint l2 = combo[(size_t)e2.x * 16 + d0];
            uint l3 = combo[(size_t)e3.x * 16 + d0];
            uint w0 = ((const ushort*)(combo + (size_t)e0.x * 16 + 8))[f];
            uint w1 = ((const ushort*)(combo + (size_t)e1.x * 16 + 8))[f];
            uint w2 = ((const ushort*)(combo + (size_t)e2.x * 16 + 8))[f];
            uint w3 = ((const ushort*)(combo + (size_t)e3.x * 16 + 8))[f];
            float vw0 = __int_as_float(e0.y) * __uint_as_float(w0 << 16);
            float vw1 = __int_as_float(e1.y) * __uint_as_float(w1 << 16);
            float vw2 = __int_as_float(e2.y) * __uint_as_float(w2 << 16);
            float vw3 = __int_as_float(e3.y) * __uint_as_float(w3 << 16);
            acc0 = fmaf(vw0, __uint_as_float(l0 << 16), acc0);
            acc1 = fmaf(vw0, __uint_as_float(l0 & 0xFFFF0000u), acc1);
            acc0 = fmaf(vw1, __uint_as_float(l1 << 16), acc0);
            acc1 = fmaf(vw1, __uint_as_float(l1 & 0xFFFF0000u), acc1);
            acc0 = fmaf(vw2, __uint_as_float(l2 << 16), acc0);
            acc1 = fmaf(vw2, __uint_as_float(l2 & 0xFFFF0000u), acc1);
            acc0 = fmaf(vw3, __uint_as_float(l3 << 16), acc0);
            acc1 = fmaf(vw3, __uint_as_float(l3 & 0xFFFF0000u), acc1);
        }
        for (; i < end; ++i) {
            int2 e = rec[i];
            uint l = combo[(size_t)e.x * 16 + d0];
            uint w = ((const ushort*)(combo + (size_t)e.x * 16 + 8))[f];
            float vw = __int_as_float(e.y) * __uint_as_float(w << 16);
            acc0 = fmaf(vw, __uint_as_float(l << 16), acc0);
            acc1 = fmaf(vw, __uint_as_float(l & 0xFFFF0000u), acc1);
        }
        __builtin_nontemporal_store(acc0, &out[(size_t)row * KOUT + lane]);
        __builtin_nontemporal_store(acc1, &out[(size_t)row * KOUT + 64 + lane]);
    }
}

extern "C" void kernel_launch(void* const* d_in, const int* in_sizes, int n_in,
                              void* d_out, int out_size, void* d_ws, size_t ws_size,
                              hipStream_t stream) {
    const float* x      = (const float*)d_in[0];
    const int*   L_rows = (const int*)  d_in[1];
    const int*   L_cols = (const int*)  d_in[2];
    const float* L_v    = (const float*)d_in[3];
    const float* eig    = (const float*)d_in[4];
    float* out = (float*)d_out;

    // workspace layout (~51.5 MB): combo 6.4 + regBc/regBr 13.4 each +
    // regA 18.0 + cursors 0.2. regA reused across passes (stream-ordered).
    uint* combo = (uint*)d_ws;                                // [N*16]      6.4 MB (64B/node)
    int2* regBc = (int2*)(combo + (size_t)N_NODES * 16);      // [NC1*CAP1] 13.4 MB
    int2* regBr = regBc + (size_t)NC1 * CAP1;                 // [NC1*CAP1] 13.4 MB
    int2* regA  = regBr + (size_t)NC1 * CAP1;                 // [NCB*CAP]  18.0 MB
    int*  gc1c  = (int*)(regA + (size_t)NCB * CAP);           // coarse cursors (col)
    int*  gc1r  = gc1c + NC1 * CPAD;                          // coarse cursors (row)
    int*  gfc   = gc1r + NC1 * CPAD;                          // final cursors (col)
    int*  gfr   = gfc + NCB * CPAD;                           // final cursors (row)

    hipMemsetAsync(gc1c, 0, (size_t)(2 * NC1 + 2 * NCB) * CPAD * sizeof(int), stream);

    wav_kernel<<<(N_NODES + 255) / 256, 256, 0, stream>>>(eig, combo);

    // Fused coarse binning: edges read once, both orderings produced
    binC2_kernel<<<NBLKA, 512, 0, stream>>>(L_rows, L_cols, L_v, gc1c, gc1r, regBc, regBr);

    // Pass 1: COLUMN ordering (fine bin -> fused sort+gather -> combo LTx)
    binF_kernel<<<NC1 * CHB, 512, 0, stream>>>(gc1c, regBc, gfc, regA);
    sortgather1_kernel<<<NCB, 256, 0, stream>>>(gfc, regA, x, combo);

    // Pass 2: ROW ordering (reusing regA)
    binF_kernel<<<NC1 * CHB, 512, 0, stream>>>(gc1r, regBr, gfr, regA);
    sortgather2_kernel<<<NCB, 256, 0, stream>>>(gfr, regA, combo, out);
}